// Round 1
// baseline (3868.883 us; speedup 1.0000x reference)
//
#include <hip/hip_runtime.h>

#define B_ 2
#define N_ 8192
#define D_ 96
#define L_ 4
#define H_ 192
#define K_ 16
#define NC_ 2
#define EPS_ 1e-5f
#define BIGF 3.402823466e38f

__device__ __forceinline__ float bn1(float x, float g, float b, float m, float v) {
  return (x - m) * (g * (1.0f / sqrtf(v + EPS_))) + b;
}

// ---------------- embed + per-point squared norm ----------------
__global__ void k_embed(const float* __restrict__ pts, const float* __restrict__ w,
                        const float* __restrict__ g, const float* __restrict__ bb,
                        const float* __restrict__ m, const float* __restrict__ v,
                        float* __restrict__ X, float* __restrict__ SQ) {
  int gid = blockIdx.x * 256 + threadIdx.x;
  int b = gid / N_, n = gid % N_;
  float p0 = pts[gid * 3], p1 = pts[gid * 3 + 1], p2 = pts[gid * 3 + 2];
  // exact numpy-order fp32 arithmetic (feeds KNN selection)
  SQ[gid] = __fadd_rn(__fadd_rn(__fmul_rn(p0, p0), __fmul_rn(p1, p1)), __fmul_rn(p2, p2));
  for (int o = 0; o < D_; ++o) {
    float e = w[o * 3] * p0 + w[o * 3 + 1] * p1 + w[o * 3 + 2] * p2;
    X[(b * D_ + o) * N_ + n] = fmaxf(bn1(e, g[o], bb[o], m[o], v[o]), 0.0f);
  }
}

// ---------------- KNN: one wave per query, top-16 by (dist, idx) ----------------
__global__ void k_knn(const float* __restrict__ pts, const float* __restrict__ SQ,
                      int* __restrict__ IDX) {
  int lane = threadIdx.x & 63;
  int g = blockIdx.x * 4 + (threadIdx.x >> 6);
  int b = g / N_, n = g % N_;
  const float* pb = pts + b * N_ * 3;
  const float* sqb = SQ + b * N_;
  float qx = pb[n * 3], qy = pb[n * 3 + 1], qz = pb[n * 3 + 2];
  float sqn = sqb[n];
  float bd[K_]; int bi[K_];
#pragma unroll
  for (int s = 0; s < K_; ++s) { bd[s] = BIGF; bi[s] = 0x7fffffff; }
  float wd = BIGF; int wi = 0x7fffffff; int wslot = 0;
  for (int j = 0; j < N_ / 64; ++j) {
    int cand = lane + j * 64;
    const float* pc = pb + cand * 3;
    float px = pc[0], py = pc[1], pz = pc[2];
    float dot = __fadd_rn(__fadd_rn(__fmul_rn(qx, px), __fmul_rn(qy, py)), __fmul_rn(qz, pz));
    float d = __fsub_rn(__fadd_rn(sqn, sqb[cand]), __fmul_rn(2.0f, dot));
    if (d < wd || (d == wd && cand < wi)) {
#pragma unroll
      for (int s = 0; s < K_; ++s) if (s == wslot) { bd[s] = d; bi[s] = cand; }
      wd = -BIGF; wi = -1;
#pragma unroll
      for (int s = 0; s < K_; ++s) {
        bool worse = (bd[s] > wd) || (bd[s] == wd && bi[s] > wi);
        if (worse) { wd = bd[s]; wi = bi[s]; wslot = s; }
      }
    }
  }
  // merge 64 lanes' top-16 -> global top-16 (ascending (d, idx), matches stable top_k)
  for (int r = 0; r < K_; ++r) {
    float md = BIGF; int mi = 0x7fffffff;
#pragma unroll
    for (int s = 0; s < K_; ++s) {
      bool better = (bd[s] < md) || (bd[s] == md && bi[s] < mi);
      if (better) { md = bd[s]; mi = bi[s]; }
    }
#pragma unroll
    for (int off = 32; off > 0; off >>= 1) {
      float od = __shfl_xor(md, off);
      int oi = __shfl_xor(mi, off);
      bool better = (od < md) || (od == md && oi < mi);
      if (better) { md = od; mi = oi; }
    }
#pragma unroll
    for (int s = 0; s < K_; ++s) if (bi[s] == mi) { bd[s] = BIGF; bi[s] = 0x7fffffff; }
    if (lane == 0) IDX[g * K_ + r] = mi;
  }
}

// ---------------- QKV: thread-per-point, x column in registers ----------------
__global__ void k_qkv(const float* __restrict__ X, const float* __restrict__ wq,
                      const float* __restrict__ wk, const float* __restrict__ wv,
                      float* __restrict__ QT, float* __restrict__ KT, float* __restrict__ VT) {
  int gid = blockIdx.x * 256 + threadIdx.x;
  int b = gid / N_, n = gid % N_;
  const float* xb = X + b * D_ * N_ + n;
  float xr[D_];
#pragma unroll
  for (int c = 0; c < D_; ++c) xr[c] = xb[c * N_];
  float* qo = QT + (size_t)gid * D_;
  float* ko = KT + (size_t)gid * D_;
  float* vo = VT + (size_t)gid * D_;
  for (int o = 0; o < D_; ++o) {
    float aq = 0.f, ak = 0.f, av = 0.f;
#pragma unroll
    for (int c = 0; c < D_; ++c) {
      float xv = xr[c];
      aq += wq[o * D_ + c] * xv;
      ak += wk[o * D_ + c] * xv;
      av += wv[o * D_ + c] * xv;
    }
    qo[o] = aq; ko[o] = ak; vo[o] = av;
  }
}

// 96x96 weight (global) times 96x16 tile (LDS); this thread produces rows r and r+48.
__device__ __forceinline__ void gemm2(const float* __restrict__ W, int r, const float* bin,
                                      float acc0[K_], float acc1[K_]) {
#pragma unroll
  for (int k = 0; k < K_; ++k) { acc0[k] = 0.f; acc1[k] = 0.f; }
  for (int c4 = 0; c4 < D_; c4 += 4) {
    float4 wa = *(const float4*)(W + r * D_ + c4);
    float4 wb = *(const float4*)(W + (r + 48) * D_ + c4);
    const float* wav = (const float*)&wa;
    const float* wbv = (const float*)&wb;
#pragma unroll
    for (int u = 0; u < 4; ++u) {
      float A = wav[u], Bv = wbv[u];
      const float4* ip = (const float4*)(bin + (c4 + u) * K_);
#pragma unroll
      for (int q = 0; q < 4; ++q) {
        float4 iv = ip[q];
        acc0[4 * q + 0] += A * iv.x;  acc0[4 * q + 1] += A * iv.y;
        acc0[4 * q + 2] += A * iv.z;  acc0[4 * q + 3] += A * iv.w;
        acc1[4 * q + 0] += Bv * iv.x; acc1[4 * q + 1] += Bv * iv.y;
        acc1[4 * q + 2] += Bv * iv.z; acc1[4 * q + 3] += Bv * iv.w;
      }
    }
  }
}

// ---------------- fused attention block: 4 points/block, 192 threads ----------------
__global__ void __launch_bounds__(192) k_attn(
    float* __restrict__ X, const float* __restrict__ QT, const float* __restrict__ KT,
    const float* __restrict__ VT, const float* __restrict__ pts, const int* __restrict__ IDX,
    const float* __restrict__ pw1, const float* __restrict__ pg, const float* __restrict__ pb_,
    const float* __restrict__ pm, const float* __restrict__ pv, const float* __restrict__ pw2,
    const float* __restrict__ aw1, const float* __restrict__ ag, const float* __restrict__ ab,
    const float* __restrict__ am, const float* __restrict__ av, const float* __restrict__ aw2,
    const float* __restrict__ g1, const float* __restrict__ b1, const float* __restrict__ m1,
    const float* __restrict__ v1) {
  __shared__ __align__(16) float bufA[4][D_ * K_];
  __shared__ __align__(16) float bufP[4][D_ * K_];
  __shared__ float pd[4][3 * K_];
  __shared__ int sid[4][K_];
  int tid = threadIdx.x;
  int p = tid / 48, r = tid % 48;
  int g = blockIdx.x * 4 + p;
  int b = g / N_, n = g % N_;

  // phase A: neighbor ids + pos_diff
  if (r < K_) {
    int nbr = IDX[g * K_ + r];
    sid[p][r] = nbr;
    const float* pq = pts + (b * N_ + n) * 3;
    const float* pn = pts + (b * N_ + nbr) * 3;
    pd[p][r]          = pq[0] - pn[0];
    pd[p][K_ + r]     = pq[1] - pn[1];
    pd[p][2 * K_ + r] = pq[2] - pn[2];
  }
  __syncthreads();

  // phase B: pe1 = pw1 @ pos_diff ; bn ; relu -> bufA
#pragma unroll
  for (int h = 0; h < 2; ++h) {
    int rr = r + h * 48;
    float w0 = pw1[rr * 3], w1 = pw1[rr * 3 + 1], w2 = pw1[rr * 3 + 2];
    float sc = pg[rr] * (1.0f / sqrtf(pv[rr] + EPS_));
    float mm = pm[rr], bo = pb_[rr];
#pragma unroll
    for (int k4 = 0; k4 < K_; k4 += 4) {
      float4 o; float* ov = (float*)&o;
#pragma unroll
      for (int u = 0; u < 4; ++u) {
        int k = k4 + u;
        float val = w0 * pd[p][k] + w1 * pd[p][K_ + k] + w2 * pd[p][2 * K_ + k];
        ov[u] = fmaxf((val - mm) * sc + bo, 0.0f);
      }
      *(float4*)&bufA[p][rr * K_ + k4] = o;
    }
  }
  __syncthreads();

  // phase C: pe2 = pw2 @ bufA
  float acc0[K_], acc1[K_];
  gemm2(pw2, r, bufA[p], acc0, acc1);
  __syncthreads();

  // phase D: bufP = pe2 ; bufA = q - k_nn + pe2
  {
    float qv0 = QT[(size_t)g * D_ + r];
    float qv1 = QT[(size_t)g * D_ + r + 48];
#pragma unroll
    for (int k4 = 0; k4 < K_; k4 += 4) {
      *(float4*)&bufP[p][r * K_ + k4]        = make_float4(acc0[k4], acc0[k4 + 1], acc0[k4 + 2], acc0[k4 + 3]);
      *(float4*)&bufP[p][(r + 48) * K_ + k4] = make_float4(acc1[k4], acc1[k4 + 1], acc1[k4 + 2], acc1[k4 + 3]);
    }
#pragma unroll
    for (int k = 0; k < K_; ++k) {
      int nbr = sid[p][k];
      const float* kt = KT + (size_t)(b * N_ + nbr) * D_;
      bufA[p][r * K_ + k]        = qv0 - kt[r] + acc0[k];
      bufA[p][(r + 48) * K_ + k] = qv1 - kt[r + 48] + acc1[k];
    }
  }
  __syncthreads();

  // phase E: t = aw1 @ bufA  (then bn+relu back into bufA)
  gemm2(aw1, r, bufA[p], acc0, acc1);
  __syncthreads();
#pragma unroll
  for (int h = 0; h < 2; ++h) {
    int rr = r + h * 48;
    float sc = ag[rr] * (1.0f / sqrtf(av[rr] + EPS_));
    float mm = am[rr], bo = ab[rr];
    float* ac = h ? acc1 : acc0;
#pragma unroll
    for (int k4 = 0; k4 < K_; k4 += 4) {
      float4 o; float* ov = (float*)&o;
#pragma unroll
      for (int u = 0; u < 4; ++u) ov[u] = fmaxf((ac[k4 + u] - mm) * sc + bo, 0.0f);
      *(float4*)&bufA[p][rr * K_ + k4] = o;
    }
  }
  __syncthreads();

  // phase F: a2 = aw2 @ bufA ; softmax over k ; out ; residual + bn -> X
  gemm2(aw2, r, bufA[p], acc0, acc1);
#pragma unroll
  for (int h = 0; h < 2; ++h) {
    int rr = r + h * 48;
    float* s = h ? acc1 : acc0;
    float mx = s[0];
#pragma unroll
    for (int k = 1; k < K_; ++k) mx = fmaxf(mx, s[k]);
    float sum = 0.f;
#pragma unroll
    for (int k = 0; k < K_; ++k) { s[k] = expf(s[k] - mx); sum += s[k]; }
    float inv = 1.0f / sum;
    float out = 0.f;
#pragma unroll
    for (int k = 0; k < K_; ++k) {
      int nbr = sid[p][k];
      out += s[k] * (VT[(size_t)(b * N_ + nbr) * D_ + rr] + bufP[p][rr * K_ + k]);
    }
    out *= inv;
    float t = X[(b * D_ + rr) * N_ + n] + out;
    X[(b * D_ + rr) * N_ + n] = (t - m1[rr]) * (g1[rr] * (1.0f / sqrtf(v1[rr] + EPS_))) + b1[rr];
  }
}

// ---------------- FFN: 2 points/block ----------------
__global__ void __launch_bounds__(192) k_ffn(
    float* __restrict__ X, const float* __restrict__ w1, const float* __restrict__ fg,
    const float* __restrict__ fb, const float* __restrict__ fm, const float* __restrict__ fv,
    const float* __restrict__ w2, const float* __restrict__ g2, const float* __restrict__ b2,
    const float* __restrict__ m2, const float* __restrict__ v2) {
  __shared__ __align__(16) float xc[2][D_];
  __shared__ __align__(16) float hbuf[2][H_];
  int tid = threadIdx.x;
  int p = tid / D_, r = tid % D_;
  int g = blockIdx.x * 2 + p;
  int b = g / N_, n = g % N_;
  xc[p][r] = X[(b * D_ + r) * N_ + n];
  __syncthreads();
#pragma unroll
  for (int h = 0; h < 2; ++h) {
    int j = r + h * D_;
    float acc = 0.f;
#pragma unroll
    for (int c4 = 0; c4 < D_; c4 += 4) {
      float4 wv4 = *(const float4*)(w1 + j * D_ + c4);
      float4 xv4 = *(const float4*)&xc[p][c4];
      acc += wv4.x * xv4.x + wv4.y * xv4.y + wv4.z * xv4.z + wv4.w * xv4.w;
    }
    hbuf[p][j] = fmaxf((acc - fm[j]) * (fg[j] * (1.0f / sqrtf(fv[j] + EPS_))) + fb[j], 0.0f);
  }
  __syncthreads();
  float acc = 0.f;
#pragma unroll
  for (int j4 = 0; j4 < H_; j4 += 4) {
    float4 wv4 = *(const float4*)(w2 + r * H_ + j4);
    float4 hv4 = *(const float4*)&hbuf[p][j4];
    acc += wv4.x * hv4.x + wv4.y * hv4.y + wv4.z * hv4.z + wv4.w * hv4.w;
  }
  float t = xc[p][r] + acc;
  X[(b * D_ + r) * N_ + n] = (t - m2[r]) * (g2[r] * (1.0f / sqrtf(v2[r] + EPS_))) + b2[r];
}

// ---------------- head ----------------
__global__ void k_head(const float* __restrict__ X, const float* __restrict__ w1,
                       const float* __restrict__ hg, const float* __restrict__ hbb,
                       const float* __restrict__ hm, const float* __restrict__ hv,
                       const float* __restrict__ w2, const float* __restrict__ hb2,
                       float* __restrict__ OUT) {
  int gid = blockIdx.x * 256 + threadIdx.x;
  int b = gid / N_, n = gid % N_;
  const float* xb = X + b * D_ * N_ + n;
  float xr[D_];
#pragma unroll
  for (int c = 0; c < D_; ++c) xr[c] = xb[c * N_];
  float a0 = 0.f, a1 = 0.f;
  for (int j = 0; j < 128; ++j) {
    float acc = 0.f;
#pragma unroll
    for (int c = 0; c < D_; ++c) acc += w1[j * D_ + c] * xr[c];
    float t = fmaxf((acc - hm[j]) * (hg[j] * (1.0f / sqrtf(hv[j] + EPS_))) + hbb[j], 0.0f);
    a0 += w2[j] * t;
    a1 += w2[128 + j] * t;
  }
  OUT[(b * NC_ + 0) * N_ + n] = a0 + hb2[0];
  OUT[(b * NC_ + 1) * N_ + n] = a1 + hb2[1];
}

extern "C" void kernel_launch(void* const* d_in, const int* in_sizes, int n_in,
                              void* d_out, int out_size, void* d_ws, size_t ws_size,
                              hipStream_t stream) {
  (void)in_sizes; (void)n_in; (void)out_size; (void)ws_size;
  const float* pts     = (const float*)d_in[0];
  const float* embed_w = (const float*)d_in[1];
  const float* embed_g = (const float*)d_in[2];
  const float* embed_b = (const float*)d_in[3];
  const float* embed_m = (const float*)d_in[4];
  const float* embed_v = (const float*)d_in[5];
  const float* wq      = (const float*)d_in[6];
  const float* wk      = (const float*)d_in[7];
  const float* wv      = (const float*)d_in[8];
  const float* pe_w1   = (const float*)d_in[9];
  const float* pe_g    = (const float*)d_in[10];
  const float* pe_b    = (const float*)d_in[11];
  const float* pe_m    = (const float*)d_in[12];
  const float* pe_v    = (const float*)d_in[13];
  const float* pe_w2   = (const float*)d_in[14];
  const float* am_w1   = (const float*)d_in[15];
  const float* am_g    = (const float*)d_in[16];
  const float* am_b    = (const float*)d_in[17];
  const float* am_m    = (const float*)d_in[18];
  const float* am_v    = (const float*)d_in[19];
  const float* am_w2   = (const float*)d_in[20];
  const float* n1_g    = (const float*)d_in[21];
  const float* n1_b    = (const float*)d_in[22];
  const float* n1_m    = (const float*)d_in[23];
  const float* n1_v    = (const float*)d_in[24];
  const float* ffn_w1  = (const float*)d_in[25];
  const float* f_g     = (const float*)d_in[26];
  const float* f_b     = (const float*)d_in[27];
  const float* f_m     = (const float*)d_in[28];
  const float* f_v     = (const float*)d_in[29];
  const float* ffn_w2  = (const float*)d_in[30];
  const float* n2_g    = (const float*)d_in[31];
  const float* n2_b    = (const float*)d_in[32];
  const float* n2_m    = (const float*)d_in[33];
  const float* n2_v    = (const float*)d_in[34];
  const float* hd_w1   = (const float*)d_in[35];
  const float* hd_g    = (const float*)d_in[36];
  const float* hd_b    = (const float*)d_in[37];
  const float* hd_m    = (const float*)d_in[38];
  const float* hd_v    = (const float*)d_in[39];
  const float* hd_w2   = (const float*)d_in[40];
  const float* hd_b2   = (const float*)d_in[41];

  float* ws = (float*)d_ws;
  float* X  = ws;
  float* QT = X  + (size_t)B_ * D_ * N_;
  float* KT = QT + (size_t)B_ * N_ * D_;
  float* VT = KT + (size_t)B_ * N_ * D_;
  float* SQ = VT + (size_t)B_ * N_ * D_;
  int*   IDX = (int*)(SQ + (size_t)B_ * N_);

  k_embed<<<B_ * N_ / 256, 256, 0, stream>>>(pts, embed_w, embed_g, embed_b, embed_m, embed_v, X, SQ);
  k_knn<<<B_ * N_ / 4, 256, 0, stream>>>(pts, SQ, IDX);
  for (int l = 0; l < L_; ++l) {
    k_qkv<<<B_ * N_ / 256, 256, 0, stream>>>(X, wq + l * D_ * D_, wk + l * D_ * D_, wv + l * D_ * D_, QT, KT, VT);
    k_attn<<<B_ * N_ / 4, 192, 0, stream>>>(X, QT, KT, VT, pts, IDX,
        pe_w1 + l * D_ * 3, pe_g + l * D_, pe_b + l * D_, pe_m + l * D_, pe_v + l * D_, pe_w2 + l * D_ * D_,
        am_w1 + l * D_ * D_, am_g + l * D_, am_b + l * D_, am_m + l * D_, am_v + l * D_, am_w2 + l * D_ * D_,
        n1_g + l * D_, n1_b + l * D_, n1_m + l * D_, n1_v + l * D_);
    k_ffn<<<B_ * N_ / 2, 192, 0, stream>>>(X, ffn_w1 + l * H_ * D_, f_g + l * H_, f_b + l * H_, f_m + l * H_, f_v + l * H_,
        ffn_w2 + l * D_ * H_, n2_g + l * D_, n2_b + l * D_, n2_m + l * D_, n2_v + l * D_);
  }
  k_head<<<B_ * N_ / 256, 256, 0, stream>>>(X, hd_w1, hd_g, hd_b, hd_m, hd_v, hd_w2, hd_b2, (float*)d_out);
}

// Round 5
// 3858.118 us; speedup vs baseline: 1.0028x; 1.0028x over previous
//
#include <hip/hip_runtime.h>

#define B_ 2
#define N_ 8192
#define D_ 96
#define L_ 4
#define H_ 192
#define K_ 16
#define NC_ 2
#define EPS_ 1e-5f
#define BIGF 3.402823466e38f

__device__ __forceinline__ float bn1(float x, float g, float b, float m, float v) {
  return (x - m) * (g * (1.0f / sqrtf(v + EPS_))) + b;
}

// ---------------- embed + per-point squared norm ----------------
__global__ void k_embed(const float* __restrict__ pts, const float* __restrict__ w,
                        const float* __restrict__ g, const float* __restrict__ bb,
                        const float* __restrict__ m, const float* __restrict__ v,
                        float* __restrict__ X, float* __restrict__ SQ) {
  int gid = blockIdx.x * 256 + threadIdx.x;
  int b = gid / N_, n = gid % N_;
  float p0 = pts[gid * 3], p1 = pts[gid * 3 + 1], p2 = pts[gid * 3 + 2];
  // exact numpy-order fp32 arithmetic (feeds KNN selection)
  SQ[gid] = __fadd_rn(__fadd_rn(__fmul_rn(p0, p0), __fmul_rn(p1, p1)), __fmul_rn(p2, p2));
  for (int o = 0; o < D_; ++o) {
    float e = w[o * 3] * p0 + w[o * 3 + 1] * p1 + w[o * 3 + 2] * p2;
    X[(b * D_ + o) * N_ + n] = fmaxf(bn1(e, g[o], bb[o], m[o], v[o]), 0.0f);
  }
}

// ---------------- KNN: one wave per query, top-16 by (dist, idx) ----------------
__global__ void k_knn(const float* __restrict__ pts, const float* __restrict__ SQ,
                      int* __restrict__ IDX) {
  int lane = threadIdx.x & 63;
  int g = blockIdx.x * 4 + (threadIdx.x >> 6);
  int b = g / N_, n = g % N_;
  const float* pb = pts + b * N_ * 3;
  const float* sqb = SQ + b * N_;
  float qx = pb[n * 3], qy = pb[n * 3 + 1], qz = pb[n * 3 + 2];
  float sqn = sqb[n];
  float bd[K_]; int bi[K_];
#pragma unroll
  for (int s = 0; s < K_; ++s) { bd[s] = BIGF; bi[s] = 0x7fffffff; }
  float wd = BIGF; int wi = 0x7fffffff; int wslot = 0;
  for (int j = 0; j < N_ / 64; ++j) {
    int cand = lane + j * 64;
    const float* pc = pb + cand * 3;
    float px = pc[0], py = pc[1], pz = pc[2];
    float dot = __fadd_rn(__fadd_rn(__fmul_rn(qx, px), __fmul_rn(qy, py)), __fmul_rn(qz, pz));
    float d = __fsub_rn(__fadd_rn(sqn, sqb[cand]), __fmul_rn(2.0f, dot));
    if (d < wd || (d == wd && cand < wi)) {
#pragma unroll
      for (int s = 0; s < K_; ++s) if (s == wslot) { bd[s] = d; bi[s] = cand; }
      wd = -BIGF; wi = -1;
#pragma unroll
      for (int s = 0; s < K_; ++s) {
        bool worse = (bd[s] > wd) || (bd[s] == wd && bi[s] > wi);
        if (worse) { wd = bd[s]; wi = bi[s]; wslot = s; }
      }
    }
  }
  // merge 64 lanes' top-16 -> global top-16 (ascending (d, idx), matches stable top_k)
  for (int r = 0; r < K_; ++r) {
    float md = BIGF; int mi = 0x7fffffff;
#pragma unroll
    for (int s = 0; s < K_; ++s) {
      bool better = (bd[s] < md) || (bd[s] == md && bi[s] < mi);
      if (better) { md = bd[s]; mi = bi[s]; }
    }
#pragma unroll
    for (int off = 32; off > 0; off >>= 1) {
      float od = __shfl_xor(md, off);
      int oi = __shfl_xor(mi, off);
      bool better = (od < md) || (od == md && oi < mi);
      if (better) { md = od; mi = oi; }
    }
#pragma unroll
    for (int s = 0; s < K_; ++s) if (bi[s] == mi) { bd[s] = BIGF; bi[s] = 0x7fffffff; }
    if (lane == 0) IDX[g * K_ + r] = mi;
  }
}

// ---------------- QKV: thread-per-point, x column in registers ----------------
__global__ void k_qkv(const float* __restrict__ X, const float* __restrict__ wq,
                      const float* __restrict__ wk, const float* __restrict__ wv,
                      float* __restrict__ QT, float* __restrict__ KT, float* __restrict__ VT) {
  int gid = blockIdx.x * 256 + threadIdx.x;
  int b = gid / N_, n = gid % N_;
  const float* xb = X + b * D_ * N_ + n;
  float xr[D_];
#pragma unroll
  for (int c = 0; c < D_; ++c) xr[c] = xb[c * N_];
  float* qo = QT + (size_t)gid * D_;
  float* ko = KT + (size_t)gid * D_;
  float* vo = VT + (size_t)gid * D_;
  for (int o = 0; o < D_; ++o) {
    float aq = 0.f, ak = 0.f, av = 0.f;
#pragma unroll
    for (int c = 0; c < D_; ++c) {
      float xv = xr[c];
      aq += wq[o * D_ + c] * xv;
      ak += wk[o * D_ + c] * xv;
      av += wv[o * D_ + c] * xv;
    }
    qo[o] = aq; ko[o] = ak; vo[o] = av;
  }
}

// 96x96 weight (global) times 96x16 tile (LDS); this thread produces rows r and r+48.
__device__ __forceinline__ void gemm2(const float* __restrict__ W, int r, const float* bin,
                                      float acc0[K_], float acc1[K_]) {
#pragma unroll
  for (int k = 0; k < K_; ++k) { acc0[k] = 0.f; acc1[k] = 0.f; }
  for (int c4 = 0; c4 < D_; c4 += 4) {
    float4 wa = *(const float4*)(W + r * D_ + c4);
    float4 wb = *(const float4*)(W + (r + 48) * D_ + c4);
    const float* wav = (const float*)&wa;
    const float* wbv = (const float*)&wb;
#pragma unroll
    for (int u = 0; u < 4; ++u) {
      float A = wav[u], Bv = wbv[u];
      const float4* ip = (const float4*)(bin + (c4 + u) * K_);
#pragma unroll
      for (int q = 0; q < 4; ++q) {
        float4 iv = ip[q];
        acc0[4 * q + 0] += A * iv.x;  acc0[4 * q + 1] += A * iv.y;
        acc0[4 * q + 2] += A * iv.z;  acc0[4 * q + 3] += A * iv.w;
        acc1[4 * q + 0] += Bv * iv.x; acc1[4 * q + 1] += Bv * iv.y;
        acc1[4 * q + 2] += Bv * iv.z; acc1[4 * q + 3] += Bv * iv.w;
      }
    }
  }
}

// ---------------- fused attention block: 4 points/block, 192 threads ----------------
__global__ void __launch_bounds__(192) k_attn(
    float* __restrict__ X, const float* __restrict__ QT, const float* __restrict__ KT,
    const float* __restrict__ VT, const float* __restrict__ pts, const int* __restrict__ IDX,
    const float* __restrict__ pw1, const float* __restrict__ pg, const float* __restrict__ pb_,
    const float* __restrict__ pm, const float* __restrict__ pv, const float* __restrict__ pw2,
    const float* __restrict__ aw1, const float* __restrict__ ag, const float* __restrict__ ab,
    const float* __restrict__ am, const float* __restrict__ av, const float* __restrict__ aw2,
    const float* __restrict__ g1, const float* __restrict__ b1, const float* __restrict__ m1,
    const float* __restrict__ v1) {
  __shared__ __align__(16) float bufA[4][D_ * K_];
  __shared__ __align__(16) float bufP[4][D_ * K_];
  __shared__ float pd[4][3 * K_];
  __shared__ int sid[4][K_];
  int tid = threadIdx.x;
  int p = tid / 48, r = tid % 48;
  int g = blockIdx.x * 4 + p;
  int b = g / N_, n = g % N_;

  // phase A: neighbor ids + pos_diff
  if (r < K_) {
    int nbr = IDX[g * K_ + r];
    sid[p][r] = nbr;
    const float* pq = pts + (b * N_ + n) * 3;
    const float* pn = pts + (b * N_ + nbr) * 3;
    pd[p][r]          = pq[0] - pn[0];
    pd[p][K_ + r]     = pq[1] - pn[1];
    pd[p][2 * K_ + r] = pq[2] - pn[2];
  }
  __syncthreads();

  // phase B: pe1 = pw1 @ pos_diff ; bn ; relu -> bufA
#pragma unroll
  for (int h = 0; h < 2; ++h) {
    int rr = r + h * 48;
    float w0 = pw1[rr * 3], w1 = pw1[rr * 3 + 1], w2 = pw1[rr * 3 + 2];
    float sc = pg[rr] * (1.0f / sqrtf(pv[rr] + EPS_));
    float mm = pm[rr], bo = pb_[rr];
#pragma unroll
    for (int k4 = 0; k4 < K_; k4 += 4) {
      float4 o; float* ov = (float*)&o;
#pragma unroll
      for (int u = 0; u < 4; ++u) {
        int k = k4 + u;
        float val = w0 * pd[p][k] + w1 * pd[p][K_ + k] + w2 * pd[p][2 * K_ + k];
        ov[u] = fmaxf((val - mm) * sc + bo, 0.0f);
      }
      *(float4*)&bufA[p][rr * K_ + k4] = o;
    }
  }
  __syncthreads();

  // phase C: pe2 = pw2 @ bufA
  float acc0[K_], acc1[K_];
  gemm2(pw2, r, bufA[p], acc0, acc1);
  __syncthreads();

  // phase D: bufP = pe2 ; bufA = q - k_nn + pe2
  {
    float qv0 = QT[(size_t)g * D_ + r];
    float qv1 = QT[(size_t)g * D_ + r + 48];
#pragma unroll
    for (int k4 = 0; k4 < K_; k4 += 4) {
      *(float4*)&bufP[p][r * K_ + k4]        = make_float4(acc0[k4], acc0[k4 + 1], acc0[k4 + 2], acc0[k4 + 3]);
      *(float4*)&bufP[p][(r + 48) * K_ + k4] = make_float4(acc1[k4], acc1[k4 + 1], acc1[k4 + 2], acc1[k4 + 3]);
    }
#pragma unroll
    for (int k = 0; k < K_; ++k) {
      int nbr = sid[p][k];
      const float* kt = KT + (size_t)(b * N_ + nbr) * D_;
      bufA[p][r * K_ + k]        = qv0 - kt[r] + acc0[k];
      bufA[p][(r + 48) * K_ + k] = qv1 - kt[r + 48] + acc1[k];
    }
  }
  __syncthreads();

  // phase E: t = aw1 @ bufA  (then bn+relu back into bufA)
  gemm2(aw1, r, bufA[p], acc0, acc1);
  __syncthreads();
#pragma unroll
  for (int h = 0; h < 2; ++h) {
    int rr = r + h * 48;
    float sc = ag[rr] * (1.0f / sqrtf(av[rr] + EPS_));
    float mm = am[rr], bo = ab[rr];
    float* ac = h ? acc1 : acc0;
#pragma unroll
    for (int k4 = 0; k4 < K_; k4 += 4) {
      float4 o; float* ov = (float*)&o;
#pragma unroll
      for (int u = 0; u < 4; ++u) ov[u] = fmaxf((ac[k4 + u] - mm) * sc + bo, 0.0f);
      *(float4*)&bufA[p][rr * K_ + k4] = o;
    }
  }
  __syncthreads();

  // phase F: a2 = aw2 @ bufA ; softmax over k ; out ; residual + bn -> X
  gemm2(aw2, r, bufA[p], acc0, acc1);
#pragma unroll
  for (int h = 0; h < 2; ++h) {
    int rr = r + h * 48;
    float* s = h ? acc1 : acc0;
    float mx = s[0];
#pragma unroll
    for (int k = 1; k < K_; ++k) mx = fmaxf(mx, s[k]);
    float sum = 0.f;
#pragma unroll
    for (int k = 0; k < K_; ++k) { s[k] = expf(s[k] - mx); sum += s[k]; }
    float inv = 1.0f / sum;
    float out = 0.f;
#pragma unroll
    for (int k = 0; k < K_; ++k) {
      int nbr = sid[p][k];
      out += s[k] * (VT[(size_t)(b * N_ + nbr) * D_ + rr] + bufP[p][rr * K_ + k]);
    }
    out *= inv;
    float t = X[(b * D_ + rr) * N_ + n] + out;
    X[(b * D_ + rr) * N_ + n] = (t - m1[rr]) * (g1[rr] * (1.0f / sqrtf(v1[rr] + EPS_))) + b1[rr];
  }
}

// ---------------- FFN: 2 points/block ----------------
__global__ void __launch_bounds__(192) k_ffn(
    float* __restrict__ X, const float* __restrict__ w1, const float* __restrict__ fg,
    const float* __restrict__ fb, const float* __restrict__ fm, const float* __restrict__ fv,
    const float* __restrict__ w2, const float* __restrict__ g2, const float* __restrict__ b2,
    const float* __restrict__ m2, const float* __restrict__ v2) {
  __shared__ __align__(16) float xc[2][D_];
  __shared__ __align__(16) float hbuf[2][H_];
  int tid = threadIdx.x;
  int p = tid / D_, r = tid % D_;
  int g = blockIdx.x * 2 + p;
  int b = g / N_, n = g % N_;
  xc[p][r] = X[(b * D_ + r) * N_ + n];
  __syncthreads();
#pragma unroll
  for (int h = 0; h < 2; ++h) {
    int j = r + h * D_;
    float acc = 0.f;
#pragma unroll
    for (int c4 = 0; c4 < D_; c4 += 4) {
      float4 wv4 = *(const float4*)(w1 + j * D_ + c4);
      float4 xv4 = *(const float4*)&xc[p][c4];
      acc += wv4.x * xv4.x + wv4.y * xv4.y + wv4.z * xv4.z + wv4.w * xv4.w;
    }
    hbuf[p][j] = fmaxf(bn1(acc, fg[j], fb[j], fm[j], fv[j]), 0.0f);
  }
  __syncthreads();
  float acc = 0.f;
#pragma unroll
  for (int j4 = 0; j4 < H_; j4 += 4) {
    float4 wv4 = *(const float4*)(w2 + r * H_ + j4);
    float4 hv4 = *(const float4*)&hbuf[p][j4];
    acc += wv4.x * hv4.x + wv4.y * hv4.y + wv4.z * hv4.z + wv4.w * hv4.w;
  }
  float t = xc[p][r] + acc;
  X[(b * D_ + r) * N_ + n] = (t - m2[r]) * (g2[r] * (1.0f / sqrtf(v2[r] + EPS_))) + b2[r];
}

// ---------------- head ----------------
__global__ void k_head(const float* __restrict__ X, const float* __restrict__ w1,
                       const float* __restrict__ hg, const float* __restrict__ hbb,
                       const float* __restrict__ hm, const float* __restrict__ hv,
                       const float* __restrict__ w2, const float* __restrict__ hb2,
                       float* __restrict__ OUT) {
  int gid = blockIdx.x * 256 + threadIdx.x;
  int b = gid / N_, n = gid % N_;
  const float* xb = X + b * D_ * N_ + n;
  float xr[D_];
#pragma unroll
  for (int c = 0; c < D_; ++c) xr[c] = xb[c * N_];
  float a0 = 0.f, a1 = 0.f;
  for (int j = 0; j < 128; ++j) {
    float acc = 0.f;
#pragma unroll
    for (int c = 0; c < D_; ++c) acc += w1[j * D_ + c] * xr[c];
    float t = fmaxf((acc - hm[j]) * (hg[j] * (1.0f / sqrtf(hv[j] + EPS_))) + hbb[j], 0.0f);
    a0 += w2[j] * t;
    a1 += w2[128 + j] * t;
  }
  OUT[(b * NC_ + 0) * N_ + n] = a0 + hb2[0];
  OUT[(b * NC_ + 1) * N_ + n] = a1 + hb2[1];
}

extern "C" void kernel_launch(void* const* d_in, const int* in_sizes, int n_in,
                              void* d_out, int out_size, void* d_ws, size_t ws_size,
                              hipStream_t stream) {
  (void)in_sizes; (void)n_in; (void)out_size;
  const float* pts     = (const float*)d_in[0];
  const float* embed_w = (const float*)d_in[1];
  const float* embed_g = (const float*)d_in[2];
  const float* embed_b = (const float*)d_in[3];
  const float* embed_m = (const float*)d_in[4];
  const float* embed_v = (const float*)d_in[5];
  const float* wq      = (const float*)d_in[6];
  const float* wk      = (const float*)d_in[7];
  const float* wv      = (const float*)d_in[8];
  const float* pe_w1   = (const float*)d_in[9];
  const float* pe_g    = (const float*)d_in[10];
  const float* pe_b    = (const float*)d_in[11];
  const float* pe_m    = (const float*)d_in[12];
  const float* pe_v    = (const float*)d_in[13];
  const float* pe_w2   = (const float*)d_in[14];
  const float* am_w1   = (const float*)d_in[15];
  const float* am_g    = (const float*)d_in[16];
  const float* am_b    = (const float*)d_in[17];
  const float* am_m    = (const float*)d_in[18];
  const float* am_v    = (const float*)d_in[19];
  const float* am_w2   = (const float*)d_in[20];
  const float* n1_g    = (const float*)d_in[21];
  const float* n1_b    = (const float*)d_in[22];
  const float* n1_m    = (const float*)d_in[23];
  const float* n1_v    = (const float*)d_in[24];
  const float* ffn_w1  = (const float*)d_in[25];
  const float* f_g     = (const float*)d_in[26];
  const float* f_b     = (const float*)d_in[27];
  const float* f_m     = (const float*)d_in[28];
  const float* f_v     = (const float*)d_in[29];
  const float* ffn_w2  = (const float*)d_in[30];
  const float* n2_g    = (const float*)d_in[31];
  const float* n2_b    = (const float*)d_in[32];
  const float* n2_m    = (const float*)d_in[33];
  const float* n2_v    = (const float*)d_in[34];
  const float* hd_w1   = (const float*)d_in[35];
  const float* hd_g    = (const float*)d_in[36];
  const float* hd_b    = (const float*)d_in[37];
  const float* hd_m    = (const float*)d_in[38];
  const float* hd_v    = (const float*)d_in[39];
  const float* hd_w2   = (const float*)d_in[40];
  const float* hd_b2   = (const float*)d_in[41];

  // ws budget: 4*B*D*N + B*N + B*N*K floats = 26,279,936 B (proven to fit in round 1)
  const size_t NEED = (size_t)(4 * B_ * D_ * N_ + B_ * N_ + B_ * N_ * K_) * 4;
  if (ws_size < NEED) return;  // diagnostic guard: clean absmax-fail instead of UB

  float* ws = (float*)d_ws;
  float* X  = ws;
  float* QT = X  + (size_t)B_ * D_ * N_;
  float* KT = QT + (size_t)B_ * N_ * D_;
  float* VT = KT + (size_t)B_ * N_ * D_;
  float* SQ = VT + (size_t)B_ * N_ * D_;
  int*   IDX = (int*)(SQ + (size_t)B_ * N_);

  k_embed<<<B_ * N_ / 256, 256, 0, stream>>>(pts, embed_w, embed_g, embed_b, embed_m, embed_v, X, SQ);
  k_knn<<<B_ * N_ / 4, 256, 0, stream>>>(pts, SQ, IDX);
  for (int l = 0; l < L_; ++l) {
    k_qkv<<<B_ * N_ / 256, 256, 0, stream>>>(X, wq + l * D_ * D_, wk + l * D_ * D_, wv + l * D_ * D_, QT, KT, VT);
    k_attn<<<B_ * N_ / 4, 192, 0, stream>>>(X, QT, KT, VT, pts, IDX,
        pe_w1 + l * D_ * 3, pe_g + l * D_, pe_b + l * D_, pe_m + l * D_, pe_v + l * D_, pe_w2 + l * D_ * D_,
        am_w1 + l * D_ * D_, am_g + l * D_, am_b + l * D_, am_m + l * D_, am_v + l * D_, am_w2 + l * D_ * D_,
        n1_g + l * D_, n1_b + l * D_, n1_m + l * D_, n1_v + l * D_);
    k_ffn<<<B_ * N_ / 2, 192, 0, stream>>>(X, ffn_w1 + l * H_ * D_, f_g + l * H_, f_b + l * H_, f_m + l * H_, f_v + l * H_,
        ffn_w2 + l * D_ * H_, n2_g + l * D_, n2_b + l * D_, n2_m + l * D_, n2_v + l * D_);
  }
  k_head<<<B_ * N_ / 256, 256, 0, stream>>>(X, hd_w1, hd_g, hd_b, hd_m, hd_v, hd_w2, hd_b2, (float*)d_out);
}